// Round 3
// baseline (518.973 us; speedup 1.0000x reference)
//
#include <hip/hip_runtime.h>
#include <hip/hip_bf16.h>

// BitLinearSTE: out[m][o] = sum_k x[m][k] * sign(w[o][k])
// M=8192, N=4096, K=4096. fp32 in/out; bf16 MFMA internally.
// GEMM: 256x256 tile, BK=64, 8 waves (2Mx4N), 4-phase/K-tile, 32x32x16 MFMA,
// counted vmcnt + counted lgkmcnt cross-phase ds prefetch, st-swizzled LDS,
// setprio, XCD swizzle, LDS-transposed vectorized epilogue.

#define M_DIM 8192
#define N_DIM 4096
#define K_DIM 4096
#define BM 256
#define BN 256
#define BK 64
#define NT (K_DIM / BK)        // 64
#define TILES_M (M_DIM / BM)   // 32
#define TILES_N (N_DIM / BN)   // 16

typedef __bf16 bf16x8 __attribute__((ext_vector_type(8)));
typedef float f32x4 __attribute__((ext_vector_type(4)));
typedef float f32x16 __attribute__((ext_vector_type(16)));

__device__ __forceinline__ void gload_lds16(const __bf16* g, __bf16* l) {
    __builtin_amdgcn_global_load_lds(
        (const __attribute__((address_space(1))) void*)g,
        (__attribute__((address_space(3))) void*)l, 16, 0, 0);
}

// ---------------- quantize kernels ----------------

__global__ __launch_bounds__(256) void quant_x_k(const float* __restrict__ x,
                                                 __bf16* __restrict__ xq, int n8) {
    int stride = gridDim.x * blockDim.x;
    for (int i = blockIdx.x * blockDim.x + threadIdx.x; i < n8; i += stride) {
        float4 v0 = reinterpret_cast<const float4*>(x)[2 * (size_t)i];
        float4 v1 = reinterpret_cast<const float4*>(x)[2 * (size_t)i + 1];
        bf16x8 o;
        o[0] = (__bf16)v0.x; o[1] = (__bf16)v0.y; o[2] = (__bf16)v0.z; o[3] = (__bf16)v0.w;
        o[4] = (__bf16)v1.x; o[5] = (__bf16)v1.y; o[6] = (__bf16)v1.z; o[7] = (__bf16)v1.w;
        *reinterpret_cast<bf16x8*>(xq + 8 * (size_t)i) = o;
    }
}

__global__ __launch_bounds__(256) void quant_w_k(const float* __restrict__ w,
                                                 __bf16* __restrict__ wq, int n8) {
    int stride = gridDim.x * blockDim.x;
    for (int i = blockIdx.x * blockDim.x + threadIdx.x; i < n8; i += stride) {
        float4 v0 = reinterpret_cast<const float4*>(w)[2 * (size_t)i];
        float4 v1 = reinterpret_cast<const float4*>(w)[2 * (size_t)i + 1];
        float f[8] = {v0.x, v0.y, v0.z, v0.w, v1.x, v1.y, v1.z, v1.w};
        bf16x8 o;
#pragma unroll
        for (int j = 0; j < 8; ++j)
            o[j] = (__bf16)((f[j] > 0.f) ? 1.f : ((f[j] < 0.f) ? -1.f : 0.f));
        *reinterpret_cast<bf16x8*>(wq + 8 * (size_t)i) = o;
    }
}

// ---------------- 256^2 GEMM, 32x32x16 MFMA ----------------
// C[M][N] = A[M][K] * B[N][K]^T.
// LDS: As[2buf][2half][128*64] + Bs same = 128 KiB.
// Swizzle: LDS (row, slot16B) holds global (row, slot ^ (row&7)); staged via
// pre-swizzled global source (linear gload_lds dest), read with the same XOR.
// Wave tile 128x64 = 4 m-tiles x 2 n-tiles of 32x32.
// A frag (mt,ks): row = mt*32 + (lane&31), k = ks*16 + (lane>>5)*8 + j.
// C/D (m74/m101): col = lane&31, row = (reg&3) + 8*(reg>>2) + 4*(lane>>5).

__global__ __launch_bounds__(512, 2) void gemm256_k(const __bf16* __restrict__ A,
                                                    const __bf16* __restrict__ B,
                                                    float* __restrict__ C) {
    extern __shared__ __bf16 sm[];
    __bf16* As = sm;
    __bf16* Bs = sm + 32768;

    int bid = blockIdx.x;
    int cpx = (TILES_M * TILES_N) >> 3;   // 64; nwg=512 % 8 == 0 -> bijective
    int swz = (bid & 7) * cpx + (bid >> 3);
    int bm = swz / TILES_N, bn = swz % TILES_N;
    const __bf16* Ag = A + (size_t)bm * BM * K_DIM;
    const __bf16* Bg = B + (size_t)bn * BN * K_DIM;

    int tid = threadIdx.x;
    int wave = tid >> 6, lane = tid & 63;
    int wm = wave >> 2, wn = wave & 3;
    int l31 = lane & 31, l7 = lane & 7, hi = lane >> 5;
    int laneRow = lane >> 3;
    int gslot8 = ((l7 ^ laneRow) << 3);   // pre-swizzled global col (elems)
    int bro = (wn & 1) * 64;              // B sub-half row origin

    // swizzled 16B-slot byte... elem offsets for ks=0..3: slot = ks*2+hi, XOR l7 (= row&7)
    int swk0 = (((0 + hi) ^ l7) << 3);
    int swk1 = (((2 + hi) ^ l7) << 3);
    int swk2 = (((4 + hi) ^ l7) << 3);
    int swk3 = (((6 + hi) ^ l7) << 3);

    f32x16 acc[4][2];
#pragma unroll
    for (int m = 0; m < 4; ++m)
#pragma unroll
        for (int n = 0; n < 2; ++n) acc[m][n] = (f32x16)(0.f);

    bf16x8 bfr[2][4];   // B frags, whole K-tile
    bf16x8 aP[4], aQ[4]; // A frag ping-pong (named: rule #20)

#define STAGE(gbase, ldsbase, kt_) do {                                               \
        const __bf16* g0_ = (gbase) + (size_t)(wave * 8 + laneRow) * K_DIM            \
                            + ((kt_) * BK + gslot8);                                  \
        gload_lds16(g0_, (ldsbase) + wave * 512);                                     \
        gload_lds16(g0_ + (size_t)64 * K_DIM, (ldsbase) + (wave + 8) * 512);          \
    } while (0)

#define RD_A(dst, base_, mt_) do {                                                    \
        const __bf16* r_ = (base_) + ((mt_) * 32 + l31) * 64;                         \
        dst[0] = *reinterpret_cast<const bf16x8*>(r_ + swk0);                         \
        dst[1] = *reinterpret_cast<const bf16x8*>(r_ + swk1);                         \
        dst[2] = *reinterpret_cast<const bf16x8*>(r_ + swk2);                         \
        dst[3] = *reinterpret_cast<const bf16x8*>(r_ + swk3);                         \
    } while (0)

#define RD_B(base_) do {                                                              \
        const __bf16* r0_ = (base_) + (bro + l31) * 64;                               \
        const __bf16* r1_ = (base_) + (bro + 32 + l31) * 64;                          \
        bfr[0][0] = *reinterpret_cast<const bf16x8*>(r0_ + swk0);                     \
        bfr[0][1] = *reinterpret_cast<const bf16x8*>(r0_ + swk1);                     \
        bfr[0][2] = *reinterpret_cast<const bf16x8*>(r0_ + swk2);                     \
        bfr[0][3] = *reinterpret_cast<const bf16x8*>(r0_ + swk3);                     \
        bfr[1][0] = *reinterpret_cast<const bf16x8*>(r1_ + swk0);                     \
        bfr[1][1] = *reinterpret_cast<const bf16x8*>(r1_ + swk1);                     \
        bfr[1][2] = *reinterpret_cast<const bf16x8*>(r1_ + swk2);                     \
        bfr[1][3] = *reinterpret_cast<const bf16x8*>(r1_ + swk3);                     \
    } while (0)

#define MFMA_PHASE(MT, AR) do {                                                       \
        __builtin_amdgcn_s_setprio(1);                                                \
        _Pragma("unroll")                                                             \
        for (int ks = 0; ks < 4; ++ks) {                                              \
            acc[MT][0] = __builtin_amdgcn_mfma_f32_32x32x16_bf16(                     \
                AR[ks], bfr[0][ks], acc[MT][0], 0, 0, 0);                             \
            acc[MT][1] = __builtin_amdgcn_mfma_f32_32x32x16_bf16(                     \
                AR[ks], bfr[1][ks], acc[MT][1], 0, 0, 0);                             \
        }                                                                             \
        __builtin_amdgcn_s_setprio(0);                                                \
    } while (0)

    // Prologue: B(0),A(0)->buf0, B(1)->buf1; wait all but B(1)'s 4 loads.
    STAGE(Bg, Bs + 0 * 8192, 0);
    STAGE(Bg + (size_t)128 * K_DIM, Bs + 1 * 8192, 0);
    STAGE(Ag, As + 0 * 8192, 0);
    STAGE(Ag + (size_t)128 * K_DIM, As + 1 * 8192, 0);
    STAGE(Bg, Bs + 2 * 8192, 1);
    STAGE(Bg + (size_t)128 * K_DIM, Bs + 3 * 8192, 1);
    asm volatile("s_waitcnt vmcnt(4)" ::: "memory");
    __builtin_amdgcn_s_barrier();

    {   // pre-issue tile-0 frag reads (B all + A m-tile 0)
        const __bf16* ap0 = As + wm * 8192;
        const __bf16* bp0 = Bs + (wn >> 1) * 8192;
        RD_B(bp0);
        RD_A(aP, ap0, 0);
    }

    for (int kt = 0; kt < NT; ++kt) {
        int b = kt & 1;
        int ktn = (kt + 1) & (NT - 1);
        int ktnn = (kt + 2) & (NT - 1);
        const __bf16* ap = As + (b * 2 + wm) * 8192;
        const __bf16* bp = Bs + (b * 2 + (wn >> 1)) * 8192;

        // q0: prefetch m1; stage A(kt+1) h0; compute m0
        RD_A(aQ, ap, 1);
        STAGE(Ag, As + ((b ^ 1) * 2 + 0) * 8192, ktn);
        __builtin_amdgcn_s_barrier();
        asm volatile("s_waitcnt lgkmcnt(4)" ::: "memory");   // aQ outstanding; older landed
        __builtin_amdgcn_sched_barrier(0);
        MFMA_PHASE(0, aP);
        __builtin_amdgcn_s_barrier();

        // q1: prefetch m2; stage A(kt+1) h1; compute m1
        RD_A(aP, ap, 2);
        STAGE(Ag + (size_t)128 * K_DIM, As + ((b ^ 1) * 2 + 1) * 8192, ktn);
        __builtin_amdgcn_s_barrier();
        asm volatile("s_waitcnt lgkmcnt(4)" ::: "memory");
        __builtin_amdgcn_sched_barrier(0);
        MFMA_PHASE(1, aQ);
        __builtin_amdgcn_s_barrier();

        // q2: prefetch m3; stage B(kt+2) h0; compute m2
        RD_A(aQ, ap, 3);
        STAGE(Bg, Bs + (b * 2 + 0) * 8192, ktnn);
        __builtin_amdgcn_s_barrier();
        asm volatile("s_waitcnt lgkmcnt(4)" ::: "memory");
        __builtin_amdgcn_sched_barrier(0);
        MFMA_PHASE(2, aP);
        __builtin_amdgcn_s_barrier();

        // q3: stage B(kt+2) h1; compute m3; counted vmcnt; cross-tile prefetch
        STAGE(Bg + (size_t)128 * K_DIM, Bs + (b * 2 + 1) * 8192, ktnn);
        __builtin_amdgcn_s_barrier();
        asm volatile("s_waitcnt lgkmcnt(0)" ::: "memory");
        __builtin_amdgcn_sched_barrier(0);
        MFMA_PHASE(3, aQ);
        asm volatile("s_waitcnt vmcnt(4)" ::: "memory");     // B(kt+2) stays in flight
        __builtin_amdgcn_s_barrier();
        if (kt + 1 < NT) {   // next buffer now valid: prefetch its B + A m0
            const __bf16* apn = As + ((b ^ 1) * 2 + wm) * 8192;
            const __bf16* bpn = Bs + ((b ^ 1) * 2 + (wn >> 1)) * 8192;
            RD_B(bpn);
            RD_A(aP, apn, 0);
        }
    }
#undef STAGE
#undef RD_A
#undef RD_B
#undef MFMA_PHASE

    // Drain all in-flight global_load_lds (all waves), then LDS is free scratch.
    asm volatile("s_waitcnt vmcnt(0)" ::: "memory");
    __builtin_amdgcn_s_barrier();

    // Epilogue: per-wave [32][32] f32 transpose in LDS -> dwordx4 stores.
    float* scr = reinterpret_cast<float*>(sm) + wave * 1024;  // 4 KB/wave
    size_t crow0 = (size_t)bm * BM + wm * 128;
    size_t ccol0 = (size_t)bn * BN + wn * 64;
#pragma unroll
    for (int mt = 0; mt < 4; ++mt)
#pragma unroll
        for (int nt = 0; nt < 2; ++nt) {
#pragma unroll
            for (int j = 0; j < 16; ++j) {
                int r = (j & 3) + 8 * (j >> 2) + 4 * hi;
                scr[r * 32 + l31] = acc[mt][nt][j];
            }
#pragma unroll
            for (int p = 0; p < 4; ++p) {
                int r = p * 8 + (lane >> 3);
                f32x4 v = *reinterpret_cast<const f32x4*>(scr + r * 32 + l7 * 4);
                *reinterpret_cast<f32x4*>(C + (crow0 + mt * 32 + r) * N_DIM
                                          + ccol0 + nt * 32 + l7 * 4) = v;
            }
        }
}

extern "C" void kernel_launch(void* const* d_in, const int* in_sizes, int n_in,
                              void* d_out, int out_size, void* d_ws, size_t ws_size,
                              hipStream_t stream) {
    const float* x = (const float*)d_in[0];
    const float* w = (const float*)d_in[1];
    float* out = (float*)d_out;

    __bf16* xq = (__bf16*)d_ws;
    __bf16* wq = xq + (size_t)M_DIM * K_DIM;

    hipFuncSetAttribute((const void*)gemm256_k,
                        hipFuncAttributeMaxDynamicSharedMemorySize, 131072);

    quant_x_k<<<2048, 256, 0, stream>>>(x, xq, (M_DIM * K_DIM) / 8);
    quant_w_k<<<1024, 256, 0, stream>>>(w, wq, (N_DIM * K_DIM) / 8);
    gemm256_k<<<TILES_M * TILES_N, 512, 131072, stream>>>(xq, wq, out);
}